// Round 5
// baseline (3686.642 us; speedup 1.0000x reference)
//
#include <hip/hip_runtime.h>
#include <hip/hip_bf16.h>

#define DEV __device__ __forceinline__

constexpr int B_ = 256;   // batch
constexpr int T_ = 512;   // time
constexpr int H_ = 128;   // GRU units
constexpr int K_ = 256;   // input dim per layer (D = 2H = 256 for all layers)
constexpr int G_ = 384;   // 3H
constexpr int M_ = B_ * T_;
constexpr int LDSROW = 72;   // ushorts per LDS tile row (gemm3: 64 data + 8 pad)
constexpr int HS = 136;      // rec h-row stride in ushorts (128 data + 8 pad)
constexpr int XPT = 16 * 3 * 128 * 16;  // xp elems per t-slice (= B_*G_ = 98304)

using bf16 = __hip_bfloat16;
typedef short bf16x8 __attribute__((ext_vector_type(8)));
typedef float f32x4 __attribute__((ext_vector_type(4)));

template <typename XT>
struct alignas(4 * sizeof(XT)) X4 {
  XT v[4];
};

DEV float tof(float x) { return x; }
DEV float tof(bf16 x) { return __bfloat162float(x); }
DEV void stor(float* p, float v) { *p = v; }
DEV void stor(bf16* p, float v) { *p = __float2bfloat16(v); }

// float -> bf16 bits, round-to-nearest-even
DEV unsigned short f2bs(float f) {
  union { float f; unsigned u; } v;
  v.f = f;
  unsigned r = (v.u + 0x7FFFu + ((v.u >> 16) & 1u)) >> 16;
  return (unsigned short)r;
}
DEV float bs2f(unsigned short s) {
  union { unsigned u; float f; } v;
  v.u = ((unsigned)s) << 16;
  return v.f;
}

DEV float fsigmoid(float x) { return 1.f / (1.f + __expf(-x)); }
DEV float ftanh(float x) {
  x = fminf(20.f, fmaxf(-20.f, x));
  float e = __expf(-2.f * x);
  return (1.f - e) / (1.f + e);
}

// Barrier draining only LDS traffic (lgkmcnt), not global loads/stores.
DEV void barrier_lds() {
  asm volatile("s_waitcnt lgkmcnt(0)\n\ts_barrier" ::: "memory");
}

DEV f32x4 mfma16(bf16x8 a, bf16x8 b, f32x4 c) {
  return __builtin_amdgcn_mfma_f32_16x16x32_bf16(a, b, c, 0, 0, 0);
}

// ---------------------------------------------------------------------------
// convX: split fp32 x[M,256] into bf16 hi/lo arrays (layer-0 GEMM input).
// ---------------------------------------------------------------------------
__global__ __launch_bounds__(256) void convX_kernel(
    const float* __restrict__ x, ushort* __restrict__ hiA,
    ushort* __restrict__ loA) {
  const int n4 = M_ * K_ / 4;
  for (int idx = blockIdx.x * blockDim.x + threadIdx.x; idx < n4;
       idx += gridDim.x * blockDim.x) {
    float4 v = ((const float4*)x)[idx];
    ushort4 h, l;
    h.x = f2bs(v.x); l.x = f2bs(v.x - bs2f(h.x));
    h.y = f2bs(v.y); l.y = f2bs(v.y - bs2f(h.y));
    h.z = f2bs(v.z); l.z = f2bs(v.z - bs2f(h.z));
    h.w = f2bs(v.w); l.w = f2bs(v.w - bs2f(h.w));
    ((ushort4*)hiA)[idx] = h;
    ((ushort4*)loA)[idx] = l;
  }
}

// ---------------------------------------------------------------------------
// convW: W[dir][256][384] fp32 -> W^T hi/lo bf16 [768 ncol][256 k].
// ---------------------------------------------------------------------------
__global__ __launch_bounds__(256) void convW_kernel(
    const float* __restrict__ W, ushort* __restrict__ WhiT,
    ushort* __restrict__ WloT) {
  const int ncol = blockIdx.x;           // 0..767
  const int dir = ncol / G_, j = ncol % G_;
  const int k = threadIdx.x;             // 0..255
  const float f = W[((size_t)dir * K_ + k) * G_ + j];
  const unsigned short hi = f2bs(f);
  WhiT[(size_t)ncol * K_ + k] = hi;
  WloT[(size_t)ncol * K_ + k] = f2bs(f - bs2f(hi));
}

// ---------------------------------------------------------------------------
// gemm3: C[M,768] = A[M,256] @ W^T' + bias, bf16 hi/lo 3-term split MFMA.
// Epilogue writes xp in rec-friendly layout [dir][t][bblk][gate j][u][s16]
// so rec's per-lane loads are contiguous b64 (4 seqs per load).
// ---------------------------------------------------------------------------
template <typename XT>
__global__ __launch_bounds__(256, 2) void gemm3_kernel(
    const ushort* __restrict__ Ahi, const ushort* __restrict__ Alo,
    const ushort* __restrict__ WhiT, const ushort* __restrict__ WloT,
    const float* __restrict__ bbias, XT* __restrict__ xp) {
  const int m0 = blockIdx.x * 128;
  const int n0 = blockIdx.y * 128;
  const int tid = threadIdx.x;
  const int w = tid >> 6, lane = tid & 63;
  const int wm = w >> 1, wn = w & 1;
  const int col = lane & 15, quad = lane >> 4;

  __shared__ __align__(16) ushort AH[128 * LDSROW];
  __shared__ __align__(16) ushort AL[128 * LDSROW];
  __shared__ __align__(16) ushort BH[128 * LDSROW];
  __shared__ __align__(16) ushort BL[128 * LDSROW];

  f32x4 acc[4][4];
#pragma unroll
  for (int i = 0; i < 4; ++i)
#pragma unroll
    for (int n = 0; n < 4; ++n) acc[i][n] = (f32x4){0.f, 0.f, 0.f, 0.f};

  const ushort* gsrc = (w == 0) ? Ahi : (w == 1) ? Alo : (w == 2) ? WhiT : WloT;
  ushort* lds = (w == 0) ? AH : (w == 1) ? AL : (w == 2) ? BH : BL;
  const int rbase = (w < 2) ? m0 : n0;

  for (int kb = 0; kb < K_; kb += 64) {
#pragma unroll
    for (int q = 0; q < 16; ++q) {
      const int slot = q * 64 + lane;
      const int r = slot >> 3, s = slot & 7;
      bf16x8 v = *(const bf16x8*)(gsrc + (size_t)(rbase + r) * K_ + kb + s * 8);
      *(bf16x8*)&lds[r * LDSROW + s * 8] = v;
    }
    __syncthreads();
#pragma unroll
    for (int z = 0; z < 2; ++z) {
      const int cc8 = (z * 4 + quad) * 8;
      bf16x8 ah[4], al[4], bh[4], bl[4];
#pragma unroll
      for (int i = 0; i < 4; ++i) {
        const int row = wm * 64 + i * 16 + col;
        ah[i] = *(const bf16x8*)&AH[row * LDSROW + cc8];
        al[i] = *(const bf16x8*)&AL[row * LDSROW + cc8];
      }
#pragma unroll
      for (int n = 0; n < 4; ++n) {
        const int row = wn * 64 + n * 16 + col;
        bh[n] = *(const bf16x8*)&BH[row * LDSROW + cc8];
        bl[n] = *(const bf16x8*)&BL[row * LDSROW + cc8];
      }
#pragma unroll
      for (int i = 0; i < 4; ++i)
#pragma unroll
        for (int n = 0; n < 4; ++n) {
          acc[i][n] = mfma16(ah[i], bh[n], acc[i][n]);
          acc[i][n] = mfma16(al[i], bh[n], acc[i][n]);
          acc[i][n] = mfma16(ah[i], bl[n], acc[i][n]);
        }
    }
    __syncthreads();
  }

  const int dir = (n0 >= G_) ? 1 : 0;
#pragma unroll
  for (int n = 0; n < 4; ++n) {
    const int ncol = n0 + wn * 64 + n * 16 + col;
    const int g = ncol - dir * G_;
    const float bv = bbias[dir * 2 * G_ + g];
    const int j = g >> 7, uu = g & 127;
#pragma unroll
    for (int i = 0; i < 4; ++i) {
      const int mb = m0 + wm * 64 + i * 16 + quad * 4;
#pragma unroll
      for (int r = 0; r < 4; ++r) {
        const int m = mb + r;
        const int bb = m >> 9;          // T_ = 512
        const int t = m & (T_ - 1);
        const int bblk = bb >> 4, s = bb & 15;
        stor(xp + (size_t)(dir * T_ + t) * XPT + bblk * (3 * 128 * 16) +
                 j * (128 * 16) + uu * 16 + s,
             acc[i][n][r] + bv);
      }
    }
  }
}

// ---------------------------------------------------------------------------
// Recurrence, v4 (MFMA). Grid (16, 2): 16 seqs/block, 512 threads (8 waves).
// Per step: h[16,128] @ U[128,384] on the matrix pipe, bf16 hi/lo 3-term.
//
// v3 post-mortem: VGPR_Count=116 < the ~160 live needed -> waves_per_eu(2)
// (min-only) let RA chase occupancy and spill the U fragments to scratch;
// (2,2) pins max occupancy so the 256-VGPR budget is actually usable.
// Also: (s&7)<<3 XOR swizzle left 8-lane aliasing on b128 A-reads (4.19M
// conflicts) -> replaced by +8-ushort row pad (HS=136): A-read start bank =
// (4*col16+16*kk+4*quad)%32 -> exactly 8 lanes/bank = wave64-b128 minimum.
// xp: new [dir][t][bblk][j][u][s16] layout -> 3 b64 loads/step (512B dense
// per wave) instead of 12 scalars; 2-deep parity-buffer prefetch (unroll-2,
// static regs) gives ~1.3 steps of HBM-latency cover.
// ---------------------------------------------------------------------------
template <typename XT, bool LAST>
__global__ __attribute__((amdgpu_flat_work_group_size(512, 512),
                          amdgpu_waves_per_eu(2, 2))) void rec_kernel(
    const XT* __restrict__ xp, const float* __restrict__ Ubase,
    const float* __restrict__ bbase, ushort* __restrict__ seqH,
    ushort* __restrict__ seqL, float* __restrict__ fin) {
  const int dir = blockIdx.y;
  const int bblk = blockIdx.x;
  const int b0 = bblk * 16;
  const float* U = Ubase + dir * (H_ * G_);      // [128 k][384 col]
  const float* bh = bbase + dir * (2 * G_) + G_; // recurrent bias [384]
  const int tid = threadIdx.x;
  const int w = tid >> 6, lane = tid & 63;
  const int col16 = lane & 15, quad = lane >> 4;
  const int u = w * 16 + col16;    // this lane's GRU unit 0..127

  __shared__ __align__(16) ushort hH[2][16 * HS];  // h hi, double-buffered
  __shared__ __align__(16) ushort hL[2][16 * HS];  // h lo

  // --- U fragments (bf16 hi/lo): B-operand, gate j, k-tile kk ---
  bf16x8 ubh[3][4], ubl[3][4];
#pragma unroll
  for (int j = 0; j < 3; ++j) {
    const int colg = j * H_ + u;
#pragma unroll
    for (int kk = 0; kk < 4; ++kk) {
      const int kbase = kk * 32 + quad * 8;
#pragma unroll
      for (int e = 0; e < 8; ++e) {
        const float f = U[(size_t)(kbase + e) * G_ + colg];
        const unsigned short hi = f2bs(f);
        ubh[j][kk][e] = (short)hi;
        ubl[j][kk][e] = (short)f2bs(f - bs2f(hi));
      }
    }
  }

  const float bz = bh[u], br = bh[H_ + u], bg = bh[2 * H_ + u];

  for (int i = tid; i < 16 * HS; i += 512) {
    hH[0][i] = 0;
    hL[0][i] = 0;
  }

  const XT* xb = xp + (size_t)dir * T_ * XPT;
  const int coff = bblk * (3 * 128 * 16) + u * 16 + quad * 4;

  X4<XT> xA[3], xB[3];
#define LOADX(dst, tn)                                  \
  {                                                     \
    const XT* p_ = xb + (size_t)(tn)*XPT + coff;        \
    dst[0] = *(const X4<XT>*)(p_);                      \
    dst[1] = *(const X4<XT>*)(p_ + 128 * 16);           \
    dst[2] = *(const X4<XT>*)(p_ + 2 * 128 * 16);       \
  }

  LOADX(xA, dir ? (T_ - 1) : 0)
  LOADX(xB, dir ? (T_ - 2) : 1)

  float hprev[4] = {0.f, 0.f, 0.f, 0.f};
  barrier_lds();

#define STEP(CUR, XBUF, ITOFF)                                               \
  {                                                                          \
    const int it_ = it + (ITOFF);                                            \
    const int t_ = dir ? (T_ - 1 - it_) : it_;                               \
    bf16x8 ah[4], al[4];                                                     \
    _Pragma("unroll") for (int kk = 0; kk < 4; ++kk) {                       \
      const int aidx = col16 * HS + kk * 32 + quad * 8;                      \
      ah[kk] = *(const bf16x8*)&hH[CUR][aidx];                               \
      al[kk] = *(const bf16x8*)&hL[CUR][aidx];                               \
    }                                                                        \
    f32x4 acc0 = {0.f, 0.f, 0.f, 0.f};                                       \
    f32x4 acc1 = {0.f, 0.f, 0.f, 0.f};                                       \
    f32x4 acc2 = {0.f, 0.f, 0.f, 0.f};                                       \
    _Pragma("unroll") for (int kk = 0; kk < 4; ++kk) {                       \
      acc0 = mfma16(ah[kk], ubh[0][kk], acc0);                               \
      acc1 = mfma16(ah[kk], ubh[1][kk], acc1);                               \
      acc2 = mfma16(ah[kk], ubh[2][kk], acc2);                               \
      acc0 = mfma16(al[kk], ubh[0][kk], acc0);                               \
      acc1 = mfma16(al[kk], ubh[1][kk], acc1);                               \
      acc2 = mfma16(al[kk], ubh[2][kk], acc2);                               \
      acc0 = mfma16(ah[kk], ubl[0][kk], acc0);                               \
      acc1 = mfma16(ah[kk], ubl[1][kk], acc1);                               \
      acc2 = mfma16(ah[kk], ubl[2][kk], acc2);                               \
    }                                                                        \
    _Pragma("unroll") for (int r = 0; r < 4; ++r) {                          \
      const float z = fsigmoid(tof(XBUF[0].v[r]) + acc0[r] + bz);            \
      const float g = fsigmoid(tof(XBUF[1].v[r]) + acc1[r] + br);            \
      const float hhv = ftanh(tof(XBUF[2].v[r]) + g * (acc2[r] + bg));       \
      const float hn = z * hprev[r] + (1.f - z) * hhv;                       \
      hprev[r] = hn;                                                         \
      const int s_ = quad * 4 + r;                                           \
      const unsigned short hi_ = f2bs(hn);                                   \
      const unsigned short lo_ = f2bs(hn - bs2f(hi_));                       \
      hH[(CUR) ^ 1][s_ * HS + u] = hi_;                                      \
      hL[(CUR) ^ 1][s_ * HS + u] = lo_;                                      \
      if constexpr (!LAST) {                                                 \
        const size_t sidx =                                                  \
            ((size_t)(b0 + s_) * T_ + t_) * (2 * H_) + dir * H_ + u;         \
        seqH[sidx] = hi_;                                                    \
        seqL[sidx] = lo_;                                                    \
      }                                                                      \
    }                                                                        \
    if (it_ + 2 < T_) LOADX(XBUF, dir ? (t_ - 2) : (t_ + 2))                 \
    barrier_lds();                                                           \
  }

  for (int it = 0; it < T_; it += 2) {
    STEP(0, xA, 0)
    STEP(1, xB, 1)
  }
#undef STEP
#undef LOADX

  if constexpr (LAST) {
#pragma unroll
    for (int r = 0; r < 4; ++r)
      fin[(size_t)(b0 + quad * 4 + r) * (2 * H_) + dir * H_ + u] = hprev[r];
  }
}

// ---------------------------------------------------------------------------
// Dense head: out[b] = sigmoid(fin[b][:] . Wd + bd)
// ---------------------------------------------------------------------------
__global__ void dense_kernel(const float* __restrict__ fin,
                             const float* __restrict__ Wd,
                             const float* __restrict__ bd,
                             float* __restrict__ out) {
  __shared__ float w[2 * H_];
  const int tid = threadIdx.x;
  w[tid] = Wd[tid];
  __syncthreads();
  float s = bd[0];
  const float* row = fin + tid * (2 * H_);
#pragma unroll 8
  for (int jj = 0; jj < 2 * H_; ++jj) s = fmaf(row[jj], w[jj], s);
  out[tid] = 1.f / (1.f + __expf(-s));
}

// ---------------------------------------------------------------------------
template <typename XT>
static void run_model(const float* x, const float* Ws, const float* Us,
                      const float* bs, const float* Wd, const float* bd,
                      float* out, char* ws, hipStream_t stream) {
  const size_t xpB = (size_t)2 * T_ * B_ * G_ * sizeof(XT);
  const size_t seqB = (size_t)B_ * T_ * 2 * H_ * 2;  // bf16 bits
  XT* xp = (XT*)ws;
  ushort* sHA = (ushort*)(ws + xpB);
  ushort* sLA = (ushort*)(ws + xpB + seqB);
  ushort* sHB = (ushort*)(ws + xpB + 2 * seqB);
  ushort* sLB = (ushort*)(ws + xpB + 3 * seqB);
  ushort* WhiT = (ushort*)(ws + xpB + 4 * seqB);
  ushort* WloT = WhiT + (size_t)768 * K_;
  float* fin = (float*)(ws + xpB + 4 * seqB + (size_t)2 * 768 * K_ * 2);

  convX_kernel<<<4096, 256, 0, stream>>>(x, sHB, sLB);

  const ushort* AHs[3] = {sHB, sHA, sHB};
  const ushort* ALs[3] = {sLB, sLA, sLB};
  ushort* oH[3] = {sHA, sHB, nullptr};
  ushort* oL[3] = {sLA, sLB, nullptr};

  for (int l = 0; l < 3; ++l) {
    const float* Wl = Ws + (size_t)l * 2 * K_ * G_;
    const float* bl = bs + (size_t)l * 4 * G_;
    const float* Ul = Us + (size_t)l * 2 * H_ * G_;
    convW_kernel<<<768, 256, 0, stream>>>(Wl, WhiT, WloT);
    gemm3_kernel<XT><<<dim3(M_ / 128, 6), 256, 0, stream>>>(
        AHs[l], ALs[l], WhiT, WloT, bl, xp);
    if (l < 2)
      rec_kernel<XT, false><<<dim3(B_ / 16, 2), 512, 0, stream>>>(
          xp, Ul, bl, oH[l], oL[l], nullptr);
    else
      rec_kernel<XT, true><<<dim3(B_ / 16, 2), 512, 0, stream>>>(
          xp, Ul, bl, nullptr, nullptr, fin);
  }
  dense_kernel<<<1, B_, 0, stream>>>(fin, Wd, bd, out);
}

extern "C" void kernel_launch(void* const* d_in, const int* in_sizes, int n_in,
                              void* d_out, int out_size, void* d_ws,
                              size_t ws_size, hipStream_t stream) {
  const float* x = (const float*)d_in[0];
  const float* Ws = (const float*)d_in[1];
  const float* Us = (const float*)d_in[2];
  const float* bs = (const float*)d_in[3];
  const float* Wd = (const float*)d_in[4];
  const float* bd = (const float*)d_in[5];
  float* out = (float*)d_out;
  char* ws = (char*)d_ws;

  const size_t seqB = (size_t)B_ * T_ * 2 * H_ * 2;
  const size_t wtB = (size_t)2 * 768 * K_ * 2;
  const size_t finB = (size_t)B_ * 2 * H_ * 4;
  const size_t xp32 = (size_t)2 * T_ * B_ * G_ * 4;
  const size_t tierA = xp32 + 4 * seqB + wtB + finB;      // ~641 MiB, fp32 xp
  if (ws_size >= tierA)
    run_model<float>(x, Ws, Us, bs, Wd, bd, out, ws, stream);
  else
    run_model<bf16>(x, Ws, Us, bs, Wd, bd, out, ws, stream);
}